// Round 7
// baseline (447.095 us; speedup 1.0000x reference)
//
#include <hip/hip_runtime.h>
#include <stdint.h>
#include <math.h>

typedef __attribute__((ext_vector_type(4))) int i32x4;
typedef __attribute__((ext_vector_type(4))) float f32x4;

#define GLD16(gp, lp)                                                     \
  __builtin_amdgcn_global_load_lds(                                       \
      (__attribute__((address_space(1))) void*)(gp),                      \
      (__attribute__((address_space(3))) void*)(lp), 16, 0, 0)

// ---------- prep W: qw = rint(clip(w*127)) -> int8, Wq[8192][4096] = [qwx|qwh]
__global__ void __launch_bounds__(256) k_prep_w(const float* __restrict__ wx,
                                                const float* __restrict__ wh,
                                                signed char* __restrict__ Wq) {
  int i = blockIdx.x * 256 + threadIdx.x;
  int e = i << 2;
  int g = e >> 12;
  int c = e & 4095;
  const float* src = (c < 2048) ? (wx + g * 2048 + c) : (wh + g * 2048 + (c - 2048));
  float4 v = *(const float4*)src;
  char4 o;
  o.x = (signed char)(int)rint(fmin(fmax((double)v.x * 127.0, -127.0), 127.0));
  o.y = (signed char)(int)rint(fmin(fmax((double)v.y * 127.0, -127.0), 127.0));
  o.z = (signed char)(int)rint(fmin(fmax((double)v.z * 127.0, -127.0), 127.0));
  o.w = (signed char)(int)rint(fmin(fmax((double)v.w * 127.0, -127.0), 127.0));
  *(char4*)(Wq + e) = o;
}

// ---------- prep A: Aq[1024][12288] = [d5|d4|d3|d2|d1|qx] int8 slices
// hx = d1*2^-4 + d2*2^-11 + d3*2^-18 + d4*2^-25 + d5*2^-32 (exact, |d|<=84)
__global__ void __launch_bounds__(256) k_prep_a(const float* __restrict__ x,
                                                const float* __restrict__ hx,
                                                signed char* __restrict__ Aq) {
  int i = blockIdx.x * 256 + threadIdx.x;   // 524288 threads
  int e = i << 2;
  int b = e >> 11;
  int c = e & 2047;
  float4 xv = *(const float4*)(x + b * 2048 + c);
  float4 hv = *(const float4*)(hx + b * 2048 + c);
  float xa[4] = {xv.x, xv.y, xv.z, xv.w};
  float ha[4] = {hv.x, hv.y, hv.z, hv.w};
  char4 q4, s1, s2, s3, s4, s5;
  signed char* qp = (signed char*)&q4;
  signed char* p1 = (signed char*)&s1;
  signed char* p2 = (signed char*)&s2;
  signed char* p3 = (signed char*)&s3;
  signed char* p4 = (signed char*)&s4;
  signed char* p5 = (signed char*)&s5;
  #pragma unroll
  for (int j = 0; j < 4; ++j) {
    qp[j] = (signed char)(int)rint(fmin(fmax((double)xa[j] * 127.0, -127.0), 127.0));
    double r = (double)ha[j];
    double d1 = rint(r * 16.0);     r -= d1 * 0x1p-4;
    double d2 = rint(r * 0x1p11);   r -= d2 * 0x1p-11;
    double d3 = rint(r * 0x1p18);   r -= d3 * 0x1p-18;
    double d4 = rint(r * 0x1p25);   r -= d4 * 0x1p-25;
    double d5 = rint(r * 0x1p32);
    p1[j] = (signed char)(int)d1;
    p2[j] = (signed char)(int)d2;
    p3[j] = (signed char)(int)d3;
    p4[j] = (signed char)(int)d4;
    p5[j] = (signed char)(int)d5;
  }
  size_t base = (size_t)b * 12288;
  *(char4*)(Aq + base + 0 * 2048 + c) = s5;   // phase 0 (smallest first)
  *(char4*)(Aq + base + 1 * 2048 + c) = s4;
  *(char4*)(Aq + base + 2 * 2048 + c) = s3;
  *(char4*)(Aq + base + 3 * 2048 + c) = s2;
  *(char4*)(Aq + base + 4 * 2048 + c) = s1;
  *(char4*)(Aq + base + 5 * 2048 + c) = q4;   // phase 5: qx
}

// ---------- fused exact i8 GEMM + LSTM epilogue ----------
// tile M=128, N=64 (4 gates x 16 j). 4 waves 2x2, wave tile 64x32.
// BK=128 i8; 96 flat K-iters; i32 exact accumulate; TwoSum Horner fold
// between digit phases (register-only); fp64 epilogue.
// NEW vs r6 (LDS-traffic attack, fixing r5's mistakes):
//  - B operand direct global->VGPR at DISTANCE 2 (loaded at iter g for
//    iter g+2), two named sets, half-loads split around the two MFMA
//    halves -> compiler emits counted vmcnt(10)/(8) waits, never drains
//    the A-prefetch queue (r5's poison was distance-1 + full drain).
//  - A-only LDS staging, DOUBLE buffer (2 x 16 KB = 32 KB): buffer re-stage
//    is separated from its last reads by the intervening barrier.
//  - LDS reads -33% (48->32 KB/block-iter), writes -33% (24->16 KB).
//  - explicit per-iter wait vmcnt(4): drains only tile g+1's 4 A-stages.
// De-phased register A-prefetch retained: ds_reads sit between s0 and s1
// MFMA clusters so LDS latency hides under the matrix pipe.
__global__ void __launch_bounds__(256, 2) k_gemm_lstm(
    const signed char* __restrict__ Aq, const signed char* __restrict__ Wq,
    const float* __restrict__ bx, const float* __restrict__ bh,
    const float* __restrict__ cx, float* __restrict__ out) {
  __shared__ __align__(16) signed char smem[32768];   // 2 x 16K A buffers

  const int t  = threadIdx.x;
  const int wv = t >> 6;
  const int ln = t & 63;
  const int wm = wv & 1;
  const int wn = wv >> 1;
  const int lr = ln & 15;
  const int q  = ln >> 4;

  const int j0 = blockIdx.x * 16;
  const int m0 = blockIdx.y * 128;

  // A staging source offsets (XOR-swizzled chunks)
  int sA[4];
  #pragma unroll
  for (int is = 0; is < 4; ++is) {
    int s = is * 256 + t;
    int r = s >> 3;
    int c = s & 7;
    int cp = c ^ (r & 7);
    sA[is] = (m0 + r) * 12288 + cp * 16;
  }

  // A LDS read offsets (s=0 half; s=1 half = offset ^ 64)
  int aoff[4];
  const int swz = lr & 7;
  #pragma unroll
  for (int mf = 0; mf < 4; ++mf)
    aoff[mf] = (wm * 64 + mf * 16 + lr) * 128 + ((q ^ swz) * 16);

  // B per-lane global base pointers: lane (lr,q) of wave (wm,wn) supplies
  // W row (gate = wn*2+nf)*2048 + j0 + lr, K-bytes q*16 of each 64-K half.
  // 4 lanes (q=0..3) cover one contiguous 64 B segment.
  const signed char* pB[2];
  #pragma unroll
  for (int nf = 0; nf < 2; ++nf)
    pB[nf] = Wq + (size_t)((wn * 2 + nf) * 2048 + j0 + lr) * 4096 + q * 16;

  i32x4 acc[4][2];
  f32x4 Hh[4][2], Hl[4][2];
  #pragma unroll
  for (int mf = 0; mf < 4; ++mf)
    #pragma unroll
    for (int nf = 0; nf < 2; ++nf)
      acc[mf][nf] = (i32x4){0, 0, 0, 0};

  // named register sets (all indices static -> stay in VGPRs)
  i32x4 Aa[4][2], Ab[4][2];   // A frags: even-iter set / odd-iter set
  i32x4 Ba[2][2], Bb[2][2];   // B frags: even-iter set / odd-iter set

  // flat K-iteration g:  kA(g) = (g>>4)*2048 + (g&15)*128
  //                      kB(g) = ((g>>4)<5 ? 2048:0) + (g&15)*128
  // prologue: stage A(0)->buf0, A(1)->buf1; load B(0)->Ba, B(1)->Bb;
  // vmcnt(12) -> A(0) done; barrier; read A(0) frags -> Aa.
  {
    #pragma unroll
    for (int is = 0; is < 4; ++is)
      GLD16(Aq + sA[is], smem + is * 4096 + wv * 1024);
    #pragma unroll
    for (int is = 0; is < 4; ++is)
      GLD16(Aq + sA[is] + 128, smem + 16384 + is * 4096 + wv * 1024);
    #pragma unroll
    for (int nf = 0; nf < 2; ++nf) {
      Ba[nf][0] = *(const i32x4*)(pB[nf] + 2048);
      Ba[nf][1] = *(const i32x4*)(pB[nf] + 2048 + 64);
    }
    #pragma unroll
    for (int nf = 0; nf < 2; ++nf) {
      Bb[nf][0] = *(const i32x4*)(pB[nf] + 2048 + 128);
      Bb[nf][1] = *(const i32x4*)(pB[nf] + 2048 + 128 + 64);
    }
  }
  asm volatile("s_waitcnt vmcnt(12)" ::: "memory");
  __builtin_amdgcn_s_barrier();
  __builtin_amdgcn_sched_barrier(0);
  {
    #pragma unroll
    for (int mf = 0; mf < 4; ++mf)
      #pragma unroll
      for (int s = 0; s < 2; ++s)
        Aa[mf][s] = *(const i32x4*)&smem[aoff[mf] ^ (s << 6)];
  }

#define FOLD(G)                                                            \
  if (((G) & 15) == 15) {                                                  \
    const int ph_ = (G) >> 4;                                              \
    if (ph_ == 0) {                                                        \
      _Pragma("unroll")                                                    \
      for (int mf = 0; mf < 4; ++mf)                                       \
        _Pragma("unroll")                                                  \
        for (int nf = 0; nf < 2; ++nf) {                                   \
          _Pragma("unroll")                                                \
          for (int r = 0; r < 4; ++r) {                                    \
            Hh[mf][nf][r] = (float)acc[mf][nf][r];                         \
            Hl[mf][nf][r] = 0.f;                                           \
          }                                                                \
          acc[mf][nf] = (i32x4){0, 0, 0, 0};                               \
        }                                                                  \
    } else if (ph_ < 5) {                                                  \
      _Pragma("unroll")                                                    \
      for (int mf = 0; mf < 4; ++mf)                                       \
        _Pragma("unroll")                                                  \
        for (int nf = 0; nf < 2; ++nf) {                                   \
          _Pragma("unroll")                                                \
          for (int r = 0; r < 4; ++r) {                                    \
            float tv = Hh[mf][nf][r] * 0x1p-7f;   /* exact (pow2) */       \
            float S  = (float)acc[mf][nf][r];     /* exact (|S|<2^25) */   \
            float sm = tv + S;                                             \
            float z  = sm - tv;                                            \
            float e  = (tv - (sm - z)) + (S - z);                          \
            Hl[mf][nf][r] = Hl[mf][nf][r] * 0x1p-7f + e;                   \
            Hh[mf][nf][r] = sm;                                            \
          }                                                                \
          acc[mf][nf] = (i32x4){0, 0, 0, 0};                               \
        }                                                                  \
    }                                                                      \
  }

// KBODY: s0 MFMA -> vmcnt(VMC) -> barrier -> stage A(G+2) -> load B(G+2)[0]
//        -> ds_read A(G+1) -> s1 MFMA -> load B(G+2)[1] -> fold.
// STGOFF/PRFOFF are compile-time buffer bases (even g: 0/16384, odd: swap).
#define KBODY(G, AC, BC, AN, STGOFF, PRFOFF, DO_STAGE, DO_LOADB, DO_PREF, VMC) \
  do {                                                                     \
    _Pragma("unroll")                                                      \
    for (int mf = 0; mf < 4; ++mf)                                         \
      _Pragma("unroll")                                                    \
      for (int nf = 0; nf < 2; ++nf)                                       \
        acc[mf][nf] = __builtin_amdgcn_mfma_i32_16x16x64_i8(               \
            AC[mf][0], BC[nf][0], acc[mf][nf], 0, 0, 0);                   \
    __builtin_amdgcn_sched_barrier(0);                                     \
    asm volatile("s_waitcnt vmcnt(" #VMC ")" ::: "memory");                \
    __builtin_amdgcn_s_barrier();   /* raw barrier: no vmcnt drain */      \
    __builtin_amdgcn_sched_barrier(0);                                     \
    const int gn_  = (G) + 2;                                              \
    const int kAn_ = (gn_ >> 4) * 2048 + ((gn_ & 15) << 7);                \
    const int kBn_ = (((gn_ >> 4) < 5) ? 2048 : 0) + ((gn_ & 15) << 7);    \
    if (DO_STAGE) {                                                        \
      _Pragma("unroll")                                                    \
      for (int is = 0; is < 4; ++is)                                       \
        GLD16(Aq + sA[is] + kAn_,                                          \
              smem + (STGOFF) + is * 4096 + wv * 1024);                    \
    }                                                                      \
    if (DO_LOADB) {  /* s0-half of B(G+2) into regs s0 just freed */       \
      _Pragma("unroll")                                                    \
      for (int nf = 0; nf < 2; ++nf)                                       \
        BC[nf][0] = *(const i32x4*)(pB[nf] + kBn_);                        \
    }                                                                      \
    if (DO_PREF) {   /* A(G+1) frags; latency hides under s1 */            \
      _Pragma("unroll")                                                    \
      for (int mf = 0; mf < 4; ++mf)                                       \
        _Pragma("unroll")                                                  \
        for (int s = 0; s < 2; ++s)                                        \
          AN[mf][s] = *(const i32x4*)&smem[(PRFOFF) + (aoff[mf] ^ (s << 6))]; \
    }                                                                      \
    __builtin_amdgcn_sched_barrier(0);                                     \
    _Pragma("unroll")                                                      \
    for (int mf = 0; mf < 4; ++mf)                                         \
      _Pragma("unroll")                                                    \
      for (int nf = 0; nf < 2; ++nf)                                       \
        acc[mf][nf] = __builtin_amdgcn_mfma_i32_16x16x64_i8(               \
            AC[mf][1], BC[nf][1], acc[mf][nf], 0, 0, 0);                   \
    if (DO_LOADB) {  /* s1-half of B(G+2) after s1 consumed old value */   \
      _Pragma("unroll")                                                    \
      for (int nf = 0; nf < 2; ++nf)                                       \
        BC[nf][1] = *(const i32x4*)(pB[nf] + kBn_ + 64);                   \
    }                                                                      \
    FOLD(G);                                                               \
  } while (0)

  #pragma unroll 1
  for (int g = 0; g < 92; g += 2) {
    KBODY(g,     Aa, Ba, Ab, 0,     16384, 1, 1, 1, 4);
    KBODY(g + 1, Ab, Bb, Aa, 16384, 0,     1, 1, 1, 4);
  }
  KBODY(92, Aa, Ba, Ab, 0,     16384, 1, 1, 1, 4);   // stages A(94), loads B(94)
  KBODY(93, Ab, Bb, Aa, 16384, 0,     1, 1, 1, 4);   // stages A(95), loads B(95)
  KBODY(94, Aa, Ba, Ab, 0,     16384, 0, 0, 1, 4);   // drain A(95), read it
  KBODY(95, Ab, Bb, Aa, 16384, 0,     0, 0, 0, 0);   // final tile, regs only
#undef KBODY
#undef FOLD
  // acc = exact Sx (i32); Hh+Hl = S_d1 + S_d2*2^-7 + ... + S_d5*2^-28

  const double invsq = 1.0 / 16129.0;     // 1/127^2
  const double hsc   = 0x1p-4 / 127.0;    // digit-chain scale

  float (*Lgo)[128][17] = (float(*)[128][17])smem;   // overlay on staging LDS

  __syncthreads();
  if (wn == 1) {   // gates g (nf=0), o (nf=1): activate, stash q*127 ints
    #pragma unroll
    for (int mf = 0; mf < 4; ++mf) {
      #pragma unroll
      for (int nf = 0; nf < 2; ++nf) {
        int gate = 2 + nf;
        int gcol = gate * 2048 + j0 + lr;
        double bsum = (double)bx[gcol] + (double)bh[gcol];
        #pragma unroll
        for (int r = 0; r < 4; ++r) {
          double Sx = (double)acc[mf][nf][r];
          double Hd = ((double)Hh[mf][nf][r] + (double)Hl[mf][nf][r]) * hsc;
          double pre = Sx * invsq + Hd + bsum;
          double av = (gate == 2) ? tanh(pre) : (1.0 / (1.0 + exp(-pre)));
          double qv = rint(fmin(fmax(av * 127.0, -127.0), 127.0));
          int m = wm * 64 + mf * 16 + q * 4 + r;
          Lgo[nf][m][lr] = (float)qv;
        }
      }
    }
  }
  __syncthreads();
  if (wn == 0) {   // gates f (nf=0), i (nf=1): combine + store
    #pragma unroll
    for (int mf = 0; mf < 4; ++mf) {
      int gcf = j0 + lr;
      int gci = 2048 + j0 + lr;
      double bf_ = (double)bx[gcf] + (double)bh[gcf];
      double bi_ = (double)bx[gci] + (double)bh[gci];
      #pragma unroll
      for (int r = 0; r < 4; ++r) {
        int m = wm * 64 + mf * 16 + q * 4 + r;
        double fpre = (double)acc[mf][0][r] * invsq +
                      ((double)Hh[mf][0][r] + (double)Hl[mf][0][r]) * hsc + bf_;
        double ipre = (double)acc[mf][1][r] * invsq +
                      ((double)Hh[mf][1][r] + (double)Hl[mf][1][r]) * hsc + bi_;
        double fs = 1.0 / (1.0 + exp(-fpre));
        double is = 1.0 / (1.0 + exp(-ipre));
        double fv = rint(fmin(fmax(fs * 127.0, -127.0), 127.0)) / 127.0;
        double iv = rint(fmin(fmax(is * 127.0, -127.0), 127.0)) / 127.0;
        double gv = (double)Lgo[0][m][lr] / 127.0;
        double ov = (double)Lgo[1][m][lr] / 127.0;
        int row = m0 + m;
        int col = j0 + lr;
        double cn = fv * (double)cx[row * 2048 + col] + iv * gv;
        double tq = rint(fmin(fmax(tanh(cn) * 127.0, -127.0), 127.0)) / 127.0;
        double hv = ov * tq;
        double cq = rint(fmin(fmax(cn * 127.0, -127.0), 127.0)) / 127.0;
        out[row * 2048 + col] = (float)hv;
        out[2097152 + row * 2048 + col] = (float)cq;
      }
    }
  }
}

// ---------- launch ----------
extern "C" void kernel_launch(void* const* d_in, const int* in_sizes, int n_in,
                              void* d_out, int out_size, void* d_ws, size_t ws_size,
                              hipStream_t stream) {
  const float* x  = (const float*)d_in[0];
  const float* hx = (const float*)d_in[1];
  const float* cx = (const float*)d_in[2];
  const float* wx = (const float*)d_in[3];
  const float* bx = (const float*)d_in[4];
  const float* wh = (const float*)d_in[5];
  const float* bh = (const float*)d_in[6];
  float* out = (float*)d_out;

  signed char* Wq = (signed char*)d_ws;                       // 33,554,432 B
  signed char* Aq = (signed char*)d_ws + 33554432;            // 12,582,912 B

  k_prep_w<<<dim3(32768), dim3(256), 0, stream>>>(wx, wh, Wq);
  k_prep_a<<<dim3(2048), dim3(256), 0, stream>>>(x, hx, Aq);
  k_gemm_lstm<<<dim3(128, 8), dim3(256), 0, stream>>>(Aq, Wq, bx, bh, cx, out);
}

// Round 9
// 378.327 us; speedup vs baseline: 1.1818x; 1.1818x over previous
//
#include <hip/hip_runtime.h>
#include <stdint.h>
#include <math.h>

typedef __attribute__((ext_vector_type(4))) int i32x4;
typedef __attribute__((ext_vector_type(4))) float f32x4;

#define GLD16(gp, lp)                                                     \
  __builtin_amdgcn_global_load_lds(                                       \
      (__attribute__((address_space(1))) void*)(gp),                      \
      (__attribute__((address_space(3))) void*)(lp), 16, 0, 0)

// ---------- prep W: qw = rint(clip(w*127)) -> int8, Wq[8192][4096] = [qwx|qwh]
__global__ void __launch_bounds__(256) k_prep_w(const float* __restrict__ wx,
                                                const float* __restrict__ wh,
                                                signed char* __restrict__ Wq) {
  int i = blockIdx.x * 256 + threadIdx.x;
  int e = i << 2;
  int g = e >> 12;
  int c = e & 4095;
  const float* src = (c < 2048) ? (wx + g * 2048 + c) : (wh + g * 2048 + (c - 2048));
  float4 v = *(const float4*)src;
  char4 o;
  o.x = (signed char)(int)rint(fmin(fmax((double)v.x * 127.0, -127.0), 127.0));
  o.y = (signed char)(int)rint(fmin(fmax((double)v.y * 127.0, -127.0), 127.0));
  o.z = (signed char)(int)rint(fmin(fmax((double)v.z * 127.0, -127.0), 127.0));
  o.w = (signed char)(int)rint(fmin(fmax((double)v.w * 127.0, -127.0), 127.0));
  *(char4*)(Wq + e) = o;
}

// ---------- prep A: Aq[1024][10240] = [d4|d3|d2|d1|qx] int8 slices
// hx ~= d1*2^-4 + d2*2^-11 + d3*2^-18 + d4*2^-25 ; residual <= 2^-26.
// Error budget: truncation adds ~5e-9 rms to pre-activations — ~30x BELOW
// the fp32 reference's own einsum accumulation noise (~1.5e-7 rms), so the
// quantization bin-flip pattern vs reference is unchanged. (3-digit variant
// rejected: its 1.1e-6 rms is 7x ABOVE ref noise -> ~500 extra bin flips.)
// Digit scales keep the 2^-7 Horner ratio so the fold code is unchanged.
__global__ void __launch_bounds__(256) k_prep_a(const float* __restrict__ x,
                                                const float* __restrict__ hx,
                                                signed char* __restrict__ Aq) {
  int i = blockIdx.x * 256 + threadIdx.x;   // 524288 threads
  int e = i << 2;
  int b = e >> 11;
  int c = e & 2047;
  float4 xv = *(const float4*)(x + b * 2048 + c);
  float4 hv = *(const float4*)(hx + b * 2048 + c);
  float xa[4] = {xv.x, xv.y, xv.z, xv.w};
  float ha[4] = {hv.x, hv.y, hv.z, hv.w};
  char4 q4, s1, s2, s3, s4;
  signed char* qp = (signed char*)&q4;
  signed char* p1 = (signed char*)&s1;
  signed char* p2 = (signed char*)&s2;
  signed char* p3 = (signed char*)&s3;
  signed char* p4 = (signed char*)&s4;
  #pragma unroll
  for (int j = 0; j < 4; ++j) {
    qp[j] = (signed char)(int)rint(fmin(fmax((double)xa[j] * 127.0, -127.0), 127.0));
    double r = (double)ha[j];
    double d1 = rint(r * 16.0);     r -= d1 * 0x1p-4;
    double d2 = rint(r * 0x1p11);   r -= d2 * 0x1p-11;
    double d3 = rint(r * 0x1p18);   r -= d3 * 0x1p-18;
    double d4 = rint(r * 0x1p25);
    p1[j] = (signed char)(int)d1;
    p2[j] = (signed char)(int)d2;
    p3[j] = (signed char)(int)d3;
    p4[j] = (signed char)(int)d4;
  }
  size_t base = (size_t)b * 10240;
  *(char4*)(Aq + base + 0 * 2048 + c) = s4;   // phase 0 (smallest first)
  *(char4*)(Aq + base + 1 * 2048 + c) = s3;
  *(char4*)(Aq + base + 2 * 2048 + c) = s2;
  *(char4*)(Aq + base + 3 * 2048 + c) = s1;
  *(char4*)(Aq + base + 4 * 2048 + c) = q4;   // phase 4: qx
}

// ---------- fused i8 GEMM + LSTM epilogue ----------
// tile M=128, N=64 (4 gates x 16 j). 4 waves 2x2, wave tile 64x32.
// BK=128 i8; 80 flat K-iters (5 phases x 16: d4,d3,d2,d1,qx); i32
// accumulate; TwoSum Horner fold between digit phases (register-only);
// fp64 epilogue.
// Structure = r6 (best, 190us at 6 phases): A and B staged via GLD16 into
// a 3 x 24 KB triple buffer; each wave holds tile g's 12 fragments in
// REGISTERS (two named sets, unroll-2 swap) and prefetches tile g+1's
// fragments from LDS during iter g:
//   MFMA s0 (regs) -> vmcnt(6) -> s_barrier -> stage(g+3 -> freed buf)
//   + ds_read(g+1 -> other reg set) -> MFMA s1 (regs) -> fold
// One barrier/iter; counted vmcnt never drains in the main loop.
// NEW vs r6: 5 phases instead of 6 (-17% MACs and LDS traffic — the LDS
// data port is the measured roofline: 72 KB/block-iter x 2 blocks/CU
// ~= the whole iteration slot at 85-128 B/cyc).
// NOTE (r5/r7 lesson): B must NOT go global->VGPR per-lane — 16 lines
// per load saturates the VMEM request path. GLD16 staging only.
__global__ void __launch_bounds__(256, 2) k_gemm_lstm(
    const signed char* __restrict__ Aq, const signed char* __restrict__ Wq,
    const float* __restrict__ bx, const float* __restrict__ bh,
    const float* __restrict__ cx, float* __restrict__ out) {
  __shared__ __align__(16) signed char smem[73728];   // 3 x (16K A + 8K B)

  const int t  = threadIdx.x;
  const int wv = t >> 6;
  const int ln = t & 63;
  const int wm = wv & 1;
  const int wn = wv >> 1;
  const int lr = ln & 15;
  const int q  = ln >> 4;

  const int j0 = blockIdx.x * 16;
  const int m0 = blockIdx.y * 128;

  // staging source offsets (XOR-swizzled chunks)
  int sA[4];
  #pragma unroll
  for (int is = 0; is < 4; ++is) {
    int s = is * 256 + t;
    int r = s >> 3;
    int c = s & 7;
    int cp = c ^ (r & 7);
    sA[is] = (m0 + r) * 10240 + cp * 16;
  }
  int sB[2];
  #pragma unroll
  for (int is = 0; is < 2; ++is) {
    int s = is * 256 + t;
    int r = s >> 3;
    int c = s & 7;
    int cp = c ^ (r & 7);
    int wrow = (r >> 4) * 2048 + j0 + (r & 15);   // gate*2048 + j
    sB[is] = wrow * 4096 + cp * 16;
  }

  // LDS read offsets (s=0 half; s=1 half = offset ^ 64)
  int aoff[4], boff[2];
  const int swz = lr & 7;
  #pragma unroll
  for (int mf = 0; mf < 4; ++mf)
    aoff[mf] = (wm * 64 + mf * 16 + lr) * 128 + ((q ^ swz) * 16);
  #pragma unroll
  for (int nf = 0; nf < 2; ++nf)
    boff[nf] = (wn * 32 + nf * 16 + lr) * 128 + ((q ^ swz) * 16);

  i32x4 acc[4][2];
  f32x4 Hh[4][2], Hl[4][2];
  #pragma unroll
  for (int mf = 0; mf < 4; ++mf)
    #pragma unroll
    for (int nf = 0; nf < 2; ++nf)
      acc[mf][nf] = (i32x4){0, 0, 0, 0};

  // two named fragment sets (all indices static -> stay in VGPRs)
  i32x4 Aa[4][2], Ba[2][2];   // even iters current
  i32x4 Ab[4][2], Bb[2][2];   // odd iters current

  // flat K-iteration g (0..79):  kA(g) = (g>>4)*2048 + (g&15)*128
  //                              kB(g) = ((g>>4)<4 ? 2048:0) + (g&15)*128
  // prologue: stage tiles 0,1,2 into b0,b1,b2; vmcnt(12) -> tile0 done;
  // barrier; read tile0 fragments into set A.
  #pragma unroll
  for (int tl = 0; tl < 3; ++tl) {
    const int kA0 = tl * 128;
    const int kB0 = 2048 + tl * 128;
    #pragma unroll
    for (int is = 0; is < 4; ++is)
      GLD16(Aq + sA[is] + kA0, smem + tl * 24576 + is * 4096 + wv * 1024);
    #pragma unroll
    for (int is = 0; is < 2; ++is)
      GLD16(Wq + sB[is] + kB0, smem + tl * 24576 + 16384 + is * 4096 + wv * 1024);
  }
  asm volatile("s_waitcnt vmcnt(12)" ::: "memory");
  __builtin_amdgcn_s_barrier();
  __builtin_amdgcn_sched_barrier(0);
  {
    const signed char* As_ = smem;
    const signed char* Bs_ = smem + 16384;
    #pragma unroll
    for (int mf = 0; mf < 4; ++mf)
      #pragma unroll
      for (int s = 0; s < 2; ++s)
        Aa[mf][s] = *(const i32x4*)&As_[aoff[mf] ^ (s << 6)];
    #pragma unroll
    for (int nf = 0; nf < 2; ++nf)
      #pragma unroll
      for (int s = 0; s < 2; ++s)
        Ba[nf][s] = *(const i32x4*)&Bs_[boff[nf] ^ (s << 6)];
  }

  int stg = 0;        // LDS base of buffer to stage tile g+3 into
  int nxt = 24576;    // LDS base of tile g+1's buffer (prefetch source)

#define FOLD(G)                                                            \
  if (((G) & 15) == 15) {                                                  \
    const int ph_ = (G) >> 4;                                              \
    if (ph_ == 0) {                                                        \
      _Pragma("unroll")                                                    \
      for (int mf = 0; mf < 4; ++mf)                                       \
        _Pragma("unroll")                                                  \
        for (int nf = 0; nf < 2; ++nf) {                                   \
          _Pragma("unroll")                                                \
          for (int r = 0; r < 4; ++r) {                                    \
            Hh[mf][nf][r] = (float)acc[mf][nf][r];                         \
            Hl[mf][nf][r] = 0.f;                                           \
          }                                                                \
          acc[mf][nf] = (i32x4){0, 0, 0, 0};                               \
        }                                                                  \
    } else if (ph_ < 4) {                                                  \
      _Pragma("unroll")                                                    \
      for (int mf = 0; mf < 4; ++mf)                                       \
        _Pragma("unroll")                                                  \
        for (int nf = 0; nf < 2; ++nf) {                                   \
          _Pragma("unroll")                                                \
          for (int r = 0; r < 4; ++r) {                                    \
            float tv = Hh[mf][nf][r] * 0x1p-7f;   /* exact (pow2) */       \
            float S  = (float)acc[mf][nf][r];     /* exact (|S|<2^20) */   \
            float sm = tv + S;                                             \
            float z  = sm - tv;                                            \
            float e  = (tv - (sm - z)) + (S - z);                          \
            Hl[mf][nf][r] = Hl[mf][nf][r] * 0x1p-7f + e;                   \
            Hh[mf][nf][r] = sm;                                            \
          }                                                                \
          acc[mf][nf] = (i32x4){0, 0, 0, 0};                               \
        }                                                                  \
    }                                                                      \
  }

#define KBODY(G, AC, BC, AN, BN, DO_STAGE, DO_PREF, VMC) do {              \
    /* s0 MFMAs: pure registers */                                         \
    _Pragma("unroll")                                                      \
    for (int mf = 0; mf < 4; ++mf)                                         \
      _Pragma("unroll")                                                    \
      for (int nf = 0; nf < 2; ++nf)                                       \
        acc[mf][nf] = __builtin_amdgcn_mfma_i32_16x16x64_i8(               \
            AC[mf][0], BC[nf][0], acc[mf][nf], 0, 0, 0);                   \
    __builtin_amdgcn_sched_barrier(0);                                     \
    asm volatile("s_waitcnt vmcnt(" #VMC ")" ::: "memory");                \
    __builtin_amdgcn_s_barrier();   /* raw barrier: no vmcnt drain */      \
    __builtin_amdgcn_sched_barrier(0);                                     \
    if (DO_STAGE) { /* stage tile G+3 into the buffer tile G vacated */    \
      const int gn_  = (G) + 3;                                            \
      const int kAn_ = (gn_ >> 4) * 2048 + ((gn_ & 15) << 7);              \
      const int kBn_ = (((gn_ >> 4) < 4) ? 2048 : 0) + ((gn_ & 15) << 7);  \
      _Pragma("unroll")                                                    \
      for (int is = 0; is < 4; ++is)                                       \
        GLD16(Aq + sA[is] + kAn_, smem + stg + is * 4096 + wv * 1024);     \
      _Pragma("unroll")                                                    \
      for (int is = 0; is < 2; ++is)                                       \
        GLD16(Wq + sB[is] + kBn_,                                          \
              smem + stg + 16384 + is * 4096 + wv * 1024);                 \
    }                                                                      \
    if (DO_PREF) { /* read tile G+1 fragments into the other reg set */    \
      const signed char* As_ = smem + nxt;                                 \
      const signed char* Bs_ = smem + nxt + 16384;                         \
      _Pragma("unroll")                                                    \
      for (int mf = 0; mf < 4; ++mf)                                       \
        _Pragma("unroll")                                                  \
        for (int s = 0; s < 2; ++s)                                        \
          AN[mf][s] = *(const i32x4*)&As_[aoff[mf] ^ (s << 6)];            \
      _Pragma("unroll")                                                    \
      for (int nf = 0; nf < 2; ++nf)                                       \
        _Pragma("unroll")                                                  \
        for (int s = 0; s < 2; ++s)                                        \
          BN[nf][s] = *(const i32x4*)&Bs_[boff[nf] ^ (s << 6)];            \
    }                                                                      \
    __builtin_amdgcn_sched_barrier(0);                                     \
    /* s1 MFMAs: pure registers (LDS latency hides under these) */         \
    _Pragma("unroll")                                                      \
    for (int mf = 0; mf < 4; ++mf)                                         \
      _Pragma("unroll")                                                    \
      for (int nf = 0; nf < 2; ++nf)                                       \
        acc[mf][nf] = __builtin_amdgcn_mfma_i32_16x16x64_i8(               \
            AC[mf][1], BC[nf][1], acc[mf][nf], 0, 0, 0);                   \
    FOLD(G);                                                               \
    stg += 24576; if (stg == 73728) stg = 0;                               \
    nxt += 24576; if (nxt == 73728) nxt = 0;                               \
  } while (0)

  #pragma unroll 1
  for (int g = 0; g < 76; g += 2) {
    KBODY(g,     Aa, Ba, Ab, Bb, 1, 1, 6);
    KBODY(g + 1, Ab, Bb, Aa, Ba, 1, 1, 6);
  }
  KBODY(76, Aa, Ba, Ab, Bb, 1, 1, 6);   // stages tile 79 (last)
  KBODY(77, Ab, Bb, Aa, Ba, 0, 1, 6);   // outstanding 78,79 -> wait 78
  KBODY(78, Aa, Ba, Ab, Bb, 0, 1, 0);   // drain tile 79, read it
  KBODY(79, Ab, Bb, Aa, Ba, 0, 0, 0);   // final tile, regs only
#undef KBODY
#undef FOLD
  // acc = exact Sx (i32); Hh+Hl = S_d1 + S_d2*2^-7 + S_d3*2^-14 + S_d4*2^-21

  const double invsq = 1.0 / 16129.0;     // 1/127^2
  const double hsc   = 0x1p-4 / 127.0;    // digit-chain scale

  float (*Lgo)[128][17] = (float(*)[128][17])smem;   // overlay on staging LDS

  __syncthreads();
  if (wn == 1) {   // gates g (nf=0), o (nf=1): activate, stash q*127 ints
    #pragma unroll
    for (int mf = 0; mf < 4; ++mf) {
      #pragma unroll
      for (int nf = 0; nf < 2; ++nf) {
        int gate = 2 + nf;
        int gcol = gate * 2048 + j0 + lr;
        double bsum = (double)bx[gcol] + (double)bh[gcol];
        #pragma unroll
        for (int r = 0; r < 4; ++r) {
          double Sx = (double)acc[mf][nf][r];
          double Hd = ((double)Hh[mf][nf][r] + (double)Hl[mf][nf][r]) * hsc;
          double pre = Sx * invsq + Hd + bsum;
          double av = (gate == 2) ? tanh(pre) : (1.0 / (1.0 + exp(-pre)));
          double qv = rint(fmin(fmax(av * 127.0, -127.0), 127.0));
          int m = wm * 64 + mf * 16 + q * 4 + r;
          Lgo[nf][m][lr] = (float)qv;
        }
      }
    }
  }
  __syncthreads();
  if (wn == 0) {   // gates f (nf=0), i (nf=1): combine + store
    #pragma unroll
    for (int mf = 0; mf < 4; ++mf) {
      int gcf = j0 + lr;
      int gci = 2048 + j0 + lr;
      double bf_ = (double)bx[gcf] + (double)bh[gcf];
      double bi_ = (double)bx[gci] + (double)bh[gci];
      #pragma unroll
      for (int r = 0; r < 4; ++r) {
        int m = wm * 64 + mf * 16 + q * 4 + r;
        double fpre = (double)acc[mf][0][r] * invsq +
                      ((double)Hh[mf][0][r] + (double)Hl[mf][0][r]) * hsc + bf_;
        double ipre = (double)acc[mf][1][r] * invsq +
                      ((double)Hh[mf][1][r] + (double)Hl[mf][1][r]) * hsc + bi_;
        double fs = 1.0 / (1.0 + exp(-fpre));
        double is = 1.0 / (1.0 + exp(-ipre));
        double fv = rint(fmin(fmax(fs * 127.0, -127.0), 127.0)) / 127.0;
        double iv = rint(fmin(fmax(is * 127.0, -127.0), 127.0)) / 127.0;
        double gv = (double)Lgo[0][m][lr] / 127.0;
        double ov = (double)Lgo[1][m][lr] / 127.0;
        int row = m0 + m;
        int col = j0 + lr;
        double cn = fv * (double)cx[row * 2048 + col] + iv * gv;
        double tq = rint(fmin(fmax(tanh(cn) * 127.0, -127.0), 127.0)) / 127.0;
        double hv = ov * tq;
        double cq = rint(fmin(fmax(cn * 127.0, -127.0), 127.0)) / 127.0;
        out[row * 2048 + col] = (float)hv;
        out[2097152 + row * 2048 + col] = (float)cq;
      }
    }
  }
}

// ---------- launch ----------
extern "C" void kernel_launch(void* const* d_in, const int* in_sizes, int n_in,
                              void* d_out, int out_size, void* d_ws, size_t ws_size,
                              hipStream_t stream) {
  const float* x  = (const float*)d_in[0];
  const float* hx = (const float*)d_in[1];
  const float* cx = (const float*)d_in[2];
  const float* wx = (const float*)d_in[3];
  const float* bx = (const float*)d_in[4];
  const float* wh = (const float*)d_in[5];
  const float* bh = (const float*)d_in[6];
  float* out = (float*)d_out;

  signed char* Wq = (signed char*)d_ws;                       // 33,554,432 B
  signed char* Aq = (signed char*)d_ws + 33554432;            // 10,485,760 B

  k_prep_w<<<dim3(32768), dim3(256), 0, stream>>>(wx, wh, Wq);
  k_prep_a<<<dim3(2048), dim3(256), 0, stream>>>(x, hx, Aq);
  k_gemm_lstm<<<dim3(128, 8), dim3(256), 0, stream>>>(Aq, Wq, bx, bh, cx, out);
}

// Round 10
// 330.246 us; speedup vs baseline: 1.3538x; 1.1456x over previous
//
#include <hip/hip_runtime.h>
#include <stdint.h>
#include <math.h>

typedef __attribute__((ext_vector_type(4))) int i32x4;
typedef __attribute__((ext_vector_type(4))) float f32x4;

#define GLD16(gp, lp)                                                     \
  __builtin_amdgcn_global_load_lds(                                       \
      (__attribute__((address_space(1))) void*)(gp),                      \
      (__attribute__((address_space(3))) void*)(lp), 16, 0, 0)

// ---------- prep W: qw = rint(clip(w*127)) -> int8, Wq[8192][4096] = [qwx|qwh]
__global__ void __launch_bounds__(256) k_prep_w(const float* __restrict__ wx,
                                                const float* __restrict__ wh,
                                                signed char* __restrict__ Wq) {
  int i = blockIdx.x * 256 + threadIdx.x;
  int e = i << 2;
  int g = e >> 12;
  int c = e & 4095;
  const float* src = (c < 2048) ? (wx + g * 2048 + c) : (wh + g * 2048 + (c - 2048));
  float4 v = *(const float4*)src;
  char4 o;
  o.x = (signed char)(int)rint(fmin(fmax((double)v.x * 127.0, -127.0), 127.0));
  o.y = (signed char)(int)rint(fmin(fmax((double)v.y * 127.0, -127.0), 127.0));
  o.z = (signed char)(int)rint(fmin(fmax((double)v.z * 127.0, -127.0), 127.0));
  o.w = (signed char)(int)rint(fmin(fmax((double)v.w * 127.0, -127.0), 127.0));
  *(char4*)(Wq + e) = o;
}

// ---------- prep A: Aq[1024][12288] rows, slots 0..4 = [d4|d3|d2|d1|qx]
// (slot 5 unused — stride kept at 12288, r6's proven layout, to control the
// one code-level variable that differed in r9's regressed run.)
// hx ~= d1*2^-4 + d2*2^-11 + d3*2^-18 + d4*2^-25 ; residual <= 2^-26.
// Error budget: truncation adds ~5e-9 rms to pre-activations — ~30x BELOW
// the fp32 reference's own einsum accumulation noise (~1.5e-7 rms); r9
// CONFIRMED numerics: absmax stayed exactly 0.015625 with 4 digits.
__global__ void __launch_bounds__(256) k_prep_a(const float* __restrict__ x,
                                                const float* __restrict__ hx,
                                                signed char* __restrict__ Aq) {
  int i = blockIdx.x * 256 + threadIdx.x;   // 524288 threads
  int e = i << 2;
  int b = e >> 11;
  int c = e & 2047;
  float4 xv = *(const float4*)(x + b * 2048 + c);
  float4 hv = *(const float4*)(hx + b * 2048 + c);
  float xa[4] = {xv.x, xv.y, xv.z, xv.w};
  float ha[4] = {hv.x, hv.y, hv.z, hv.w};
  char4 q4, s1, s2, s3, s4;
  signed char* qp = (signed char*)&q4;
  signed char* p1 = (signed char*)&s1;
  signed char* p2 = (signed char*)&s2;
  signed char* p3 = (signed char*)&s3;
  signed char* p4 = (signed char*)&s4;
  #pragma unroll
  for (int j = 0; j < 4; ++j) {
    qp[j] = (signed char)(int)rint(fmin(fmax((double)xa[j] * 127.0, -127.0), 127.0));
    double r = (double)ha[j];
    double d1 = rint(r * 16.0);     r -= d1 * 0x1p-4;
    double d2 = rint(r * 0x1p11);   r -= d2 * 0x1p-11;
    double d3 = rint(r * 0x1p18);   r -= d3 * 0x1p-18;
    double d4 = rint(r * 0x1p25);
    p1[j] = (signed char)(int)d1;
    p2[j] = (signed char)(int)d2;
    p3[j] = (signed char)(int)d3;
    p4[j] = (signed char)(int)d4;
  }
  size_t base = (size_t)b * 12288;
  *(char4*)(Aq + base + 0 * 2048 + c) = s4;   // phase 0 (smallest first)
  *(char4*)(Aq + base + 1 * 2048 + c) = s3;
  *(char4*)(Aq + base + 2 * 2048 + c) = s2;
  *(char4*)(Aq + base + 3 * 2048 + c) = s1;
  *(char4*)(Aq + base + 4 * 2048 + c) = q4;   // phase 4: qx
}

// ---------- fused i8 GEMM + LSTM epilogue ----------
// tile M=128, N=64 (4 gates x 16 j). 4 waves 2x2, wave tile 64x32.
// BK=128 i8; 80 flat K-iters (5 phases x 16: d4,d3,d2,d1,qx); i32
// accumulate; TwoSum Horner fold between digit phases (register-only);
// fp64 epilogue.
// Structure = r6 (best, 190us): A and B staged via GLD16 into a 3 x 24 KB
// triple buffer; each wave holds tile g's 12 fragments in REGISTERS (two
// named sets, unroll-2 swap) and prefetches tile g+1's fragments from LDS
// during iter g:
//   MFMA s0 (regs) -> vmcnt(6) -> s_barrier -> stage(g+3 -> freed buf)
//   + ds_read(g+1 -> other reg set) -> MFMA s1 (regs) -> fold
// One barrier/iter; counted vmcnt never drains in the main loop.
// vs r9 (289us, confounded): ONLY change is Aq stride back to 12288 —
// controlled experiment separating {environmental throttle} from {stride
// pathology}. 5-phase work cut retained (numerics r9-validated).
// NOTE (r5/r7 lesson): B must NOT go global->VGPR per-lane — 16 lines
// per load saturates the VMEM request path. GLD16 staging only.
__global__ void __launch_bounds__(256, 2) k_gemm_lstm(
    const signed char* __restrict__ Aq, const signed char* __restrict__ Wq,
    const float* __restrict__ bx, const float* __restrict__ bh,
    const float* __restrict__ cx, float* __restrict__ out) {
  __shared__ __align__(16) signed char smem[73728];   // 3 x (16K A + 8K B)

  const int t  = threadIdx.x;
  const int wv = t >> 6;
  const int ln = t & 63;
  const int wm = wv & 1;
  const int wn = wv >> 1;
  const int lr = ln & 15;
  const int q  = ln >> 4;

  const int j0 = blockIdx.x * 16;
  const int m0 = blockIdx.y * 128;

  // staging source offsets (XOR-swizzled chunks)
  int sA[4];
  #pragma unroll
  for (int is = 0; is < 4; ++is) {
    int s = is * 256 + t;
    int r = s >> 3;
    int c = s & 7;
    int cp = c ^ (r & 7);
    sA[is] = (m0 + r) * 12288 + cp * 16;
  }
  int sB[2];
  #pragma unroll
  for (int is = 0; is < 2; ++is) {
    int s = is * 256 + t;
    int r = s >> 3;
    int c = s & 7;
    int cp = c ^ (r & 7);
    int wrow = (r >> 4) * 2048 + j0 + (r & 15);   // gate*2048 + j
    sB[is] = wrow * 4096 + cp * 16;
  }

  // LDS read offsets (s=0 half; s=1 half = offset ^ 64)
  int aoff[4], boff[2];
  const int swz = lr & 7;
  #pragma unroll
  for (int mf = 0; mf < 4; ++mf)
    aoff[mf] = (wm * 64 + mf * 16 + lr) * 128 + ((q ^ swz) * 16);
  #pragma unroll
  for (int nf = 0; nf < 2; ++nf)
    boff[nf] = (wn * 32 + nf * 16 + lr) * 128 + ((q ^ swz) * 16);

  i32x4 acc[4][2];
  f32x4 Hh[4][2], Hl[4][2];
  #pragma unroll
  for (int mf = 0; mf < 4; ++mf)
    #pragma unroll
    for (int nf = 0; nf < 2; ++nf)
      acc[mf][nf] = (i32x4){0, 0, 0, 0};

  // two named fragment sets (all indices static -> stay in VGPRs)
  i32x4 Aa[4][2], Ba[2][2];   // even iters current
  i32x4 Ab[4][2], Bb[2][2];   // odd iters current

  // flat K-iteration g (0..79):  kA(g) = (g>>4)*2048 + (g&15)*128
  //                              kB(g) = ((g>>4)<4 ? 2048:0) + (g&15)*128
  // prologue: stage tiles 0,1,2 into b0,b1,b2; vmcnt(12) -> tile0 done;
  // barrier; read tile0 fragments into set A.
  #pragma unroll
  for (int tl = 0; tl < 3; ++tl) {
    const int kA0 = tl * 128;
    const int kB0 = 2048 + tl * 128;
    #pragma unroll
    for (int is = 0; is < 4; ++is)
      GLD16(Aq + sA[is] + kA0, smem + tl * 24576 + is * 4096 + wv * 1024);
    #pragma unroll
    for (int is = 0; is < 2; ++is)
      GLD16(Wq + sB[is] + kB0, smem + tl * 24576 + 16384 + is * 4096 + wv * 1024);
  }
  asm volatile("s_waitcnt vmcnt(12)" ::: "memory");
  __builtin_amdgcn_s_barrier();
  __builtin_amdgcn_sched_barrier(0);
  {
    const signed char* As_ = smem;
    const signed char* Bs_ = smem + 16384;
    #pragma unroll
    for (int mf = 0; mf < 4; ++mf)
      #pragma unroll
      for (int s = 0; s < 2; ++s)
        Aa[mf][s] = *(const i32x4*)&As_[aoff[mf] ^ (s << 6)];
    #pragma unroll
    for (int nf = 0; nf < 2; ++nf)
      #pragma unroll
      for (int s = 0; s < 2; ++s)
        Ba[nf][s] = *(const i32x4*)&Bs_[boff[nf] ^ (s << 6)];
  }

  int stg = 0;        // LDS base of buffer to stage tile g+3 into
  int nxt = 24576;    // LDS base of tile g+1's buffer (prefetch source)

#define FOLD(G)                                                            \
  if (((G) & 15) == 15) {                                                  \
    const int ph_ = (G) >> 4;                                              \
    if (ph_ == 0) {                                                        \
      _Pragma("unroll")                                                    \
      for (int mf = 0; mf < 4; ++mf)                                       \
        _Pragma("unroll")                                                  \
        for (int nf = 0; nf < 2; ++nf) {                                   \
          _Pragma("unroll")                                                \
          for (int r = 0; r < 4; ++r) {                                    \
            Hh[mf][nf][r] = (float)acc[mf][nf][r];                         \
            Hl[mf][nf][r] = 0.f;                                           \
          }                                                                \
          acc[mf][nf] = (i32x4){0, 0, 0, 0};                               \
        }                                                                  \
    } else if (ph_ < 4) {                                                  \
      _Pragma("unroll")                                                    \
      for (int mf = 0; mf < 4; ++mf)                                       \
        _Pragma("unroll")                                                  \
        for (int nf = 0; nf < 2; ++nf) {                                   \
          _Pragma("unroll")                                                \
          for (int r = 0; r < 4; ++r) {                                    \
            float tv = Hh[mf][nf][r] * 0x1p-7f;   /* exact (pow2) */       \
            float S  = (float)acc[mf][nf][r];     /* exact (|S|<2^20) */   \
            float sm = tv + S;                                             \
            float z  = sm - tv;                                            \
            float e  = (tv - (sm - z)) + (S - z);                          \
            Hl[mf][nf][r] = Hl[mf][nf][r] * 0x1p-7f + e;                   \
            Hh[mf][nf][r] = sm;                                            \
          }                                                                \
          acc[mf][nf] = (i32x4){0, 0, 0, 0};                               \
        }                                                                  \
    }                                                                      \
  }

#define KBODY(G, AC, BC, AN, BN, DO_STAGE, DO_PREF, VMC) do {              \
    /* s0 MFMAs: pure registers */                                         \
    _Pragma("unroll")                                                      \
    for (int mf = 0; mf < 4; ++mf)                                         \
      _Pragma("unroll")                                                    \
      for (int nf = 0; nf < 2; ++nf)                                       \
        acc[mf][nf] = __builtin_amdgcn_mfma_i32_16x16x64_i8(               \
            AC[mf][0], BC[nf][0], acc[mf][nf], 0, 0, 0);                   \
    __builtin_amdgcn_sched_barrier(0);                                     \
    asm volatile("s_waitcnt vmcnt(" #VMC ")" ::: "memory");                \
    __builtin_amdgcn_s_barrier();   /* raw barrier: no vmcnt drain */      \
    __builtin_amdgcn_sched_barrier(0);                                     \
    if (DO_STAGE) { /* stage tile G+3 into the buffer tile G vacated */    \
      const int gn_  = (G) + 3;                                            \
      const int kAn_ = (gn_ >> 4) * 2048 + ((gn_ & 15) << 7);              \
      const int kBn_ = (((gn_ >> 4) < 4) ? 2048 : 0) + ((gn_ & 15) << 7);  \
      _Pragma("unroll")                                                    \
      for (int is = 0; is < 4; ++is)                                       \
        GLD16(Aq + sA[is] + kAn_, smem + stg + is * 4096 + wv * 1024);     \
      _Pragma("unroll")                                                    \
      for (int is = 0; is < 2; ++is)                                       \
        GLD16(Wq + sB[is] + kBn_,                                          \
              smem + stg + 16384 + is * 4096 + wv * 1024);                 \
    }                                                                      \
    if (DO_PREF) { /* read tile G+1 fragments into the other reg set */    \
      const signed char* As_ = smem + nxt;                                 \
      const signed char* Bs_ = smem + nxt + 16384;                         \
      _Pragma("unroll")                                                    \
      for (int mf = 0; mf < 4; ++mf)                                       \
        _Pragma("unroll")                                                  \
        for (int s = 0; s < 2; ++s)                                        \
          AN[mf][s] = *(const i32x4*)&As_[aoff[mf] ^ (s << 6)];            \
      _Pragma("unroll")                                                    \
      for (int nf = 0; nf < 2; ++nf)                                       \
        _Pragma("unroll")                                                  \
        for (int s = 0; s < 2; ++s)                                        \
          BN[nf][s] = *(const i32x4*)&Bs_[boff[nf] ^ (s << 6)];            \
    }                                                                      \
    __builtin_amdgcn_sched_barrier(0);                                     \
    /* s1 MFMAs: pure registers (LDS latency hides under these) */         \
    _Pragma("unroll")                                                      \
    for (int mf = 0; mf < 4; ++mf)                                         \
      _Pragma("unroll")                                                    \
      for (int nf = 0; nf < 2; ++nf)                                       \
        acc[mf][nf] = __builtin_amdgcn_mfma_i32_16x16x64_i8(               \
            AC[mf][1], BC[nf][1], acc[mf][nf], 0, 0, 0);                   \
    FOLD(G);                                                               \
    stg += 24576; if (stg == 73728) stg = 0;                               \
    nxt += 24576; if (nxt == 73728) nxt = 0;                               \
  } while (0)

  #pragma unroll 1
  for (int g = 0; g < 76; g += 2) {
    KBODY(g,     Aa, Ba, Ab, Bb, 1, 1, 6);
    KBODY(g + 1, Ab, Bb, Aa, Ba, 1, 1, 6);
  }
  KBODY(76, Aa, Ba, Ab, Bb, 1, 1, 6);   // stages tile 79 (last)
  KBODY(77, Ab, Bb, Aa, Ba, 0, 1, 6);   // outstanding 78,79 -> wait 78
  KBODY(78, Aa, Ba, Ab, Bb, 0, 1, 0);   // drain tile 79, read it
  KBODY(79, Ab, Bb, Aa, Ba, 0, 0, 0);   // final tile, regs only
#undef KBODY
#undef FOLD
  // acc = exact Sx (i32); Hh+Hl = S_d1 + S_d2*2^-7 + S_d3*2^-14 + S_d4*2^-21

  const double invsq = 1.0 / 16129.0;     // 1/127^2
  const double hsc   = 0x1p-4 / 127.0;    // digit-chain scale

  float (*Lgo)[128][17] = (float(*)[128][17])smem;   // overlay on staging LDS

  __syncthreads();
  if (wn == 1) {   // gates g (nf=0), o (nf=1): activate, stash q*127 ints
    #pragma unroll
    for (int mf = 0; mf < 4; ++mf) {
      #pragma unroll
      for (int nf = 0; nf < 2; ++nf) {
        int gate = 2 + nf;
        int gcol = gate * 2048 + j0 + lr;
        double bsum = (double)bx[gcol] + (double)bh[gcol];
        #pragma unroll
        for (int r = 0; r < 4; ++r) {
          double Sx = (double)acc[mf][nf][r];
          double Hd = ((double)Hh[mf][nf][r] + (double)Hl[mf][nf][r]) * hsc;
          double pre = Sx * invsq + Hd + bsum;
          double av = (gate == 2) ? tanh(pre) : (1.0 / (1.0 + exp(-pre)));
          double qv = rint(fmin(fmax(av * 127.0, -127.0), 127.0));
          int m = wm * 64 + mf * 16 + q * 4 + r;
          Lgo[nf][m][lr] = (float)qv;
        }
      }
    }
  }
  __syncthreads();
  if (wn == 0) {   // gates f (nf=0), i (nf=1): combine + store
    #pragma unroll
    for (int mf = 0; mf < 4; ++mf) {
      int gcf = j0 + lr;
      int gci = 2048 + j0 + lr;
      double bf_ = (double)bx[gcf] + (double)bh[gcf];
      double bi_ = (double)bx[gci] + (double)bh[gci];
      #pragma unroll
      for (int r = 0; r < 4; ++r) {
        int m = wm * 64 + mf * 16 + q * 4 + r;
        double fpre = (double)acc[mf][0][r] * invsq +
                      ((double)Hh[mf][0][r] + (double)Hl[mf][0][r]) * hsc + bf_;
        double ipre = (double)acc[mf][1][r] * invsq +
                      ((double)Hh[mf][1][r] + (double)Hl[mf][1][r]) * hsc + bi_;
        double fs = 1.0 / (1.0 + exp(-fpre));
        double is = 1.0 / (1.0 + exp(-ipre));
        double fv = rint(fmin(fmax(fs * 127.0, -127.0), 127.0)) / 127.0;
        double iv = rint(fmin(fmax(is * 127.0, -127.0), 127.0)) / 127.0;
        double gv = (double)Lgo[0][m][lr] / 127.0;
        double ov = (double)Lgo[1][m][lr] / 127.0;
        int row = m0 + m;
        int col = j0 + lr;
        double cn = fv * (double)cx[row * 2048 + col] + iv * gv;
        double tq = rint(fmin(fmax(tanh(cn) * 127.0, -127.0), 127.0)) / 127.0;
        double hv = ov * tq;
        double cq = rint(fmin(fmax(cn * 127.0, -127.0), 127.0)) / 127.0;
        out[row * 2048 + col] = (float)hv;
        out[2097152 + row * 2048 + col] = (float)cq;
      }
    }
  }
}

// ---------- launch ----------
extern "C" void kernel_launch(void* const* d_in, const int* in_sizes, int n_in,
                              void* d_out, int out_size, void* d_ws, size_t ws_size,
                              hipStream_t stream) {
  const float* x  = (const float*)d_in[0];
  const float* hx = (const float*)d_in[1];
  const float* cx = (const float*)d_in[2];
  const float* wx = (const float*)d_in[3];
  const float* bx = (const float*)d_in[4];
  const float* wh = (const float*)d_in[5];
  const float* bh = (const float*)d_in[6];
  float* out = (float*)d_out;

  signed char* Wq = (signed char*)d_ws;                       // 33,554,432 B
  signed char* Aq = (signed char*)d_ws + 33554432;            // 12,582,912 B

  k_prep_w<<<dim3(32768), dim3(256), 0, stream>>>(wx, wh, Wq);
  k_prep_a<<<dim3(2048), dim3(256), 0, stream>>>(x, hx, Aq);
  k_gemm_lstm<<<dim3(128, 8), dim3(256), 0, stream>>>(Aq, Wq, bx, bh, cx, out);
}